// Round 9
// baseline (102.149 us; speedup 1.0000x reference)
//
#include <hip/hip_runtime.h>
#include <hip/hip_bf16.h>
#include <cstdint>
#include <cstddef>

// Problem constants
#define B_    16
#define CIN   960
#define HH    56
#define WW_   56
#define GG    2
#define COUT  96
#define NK_   5
#define PIX   3136   // 56*56
#define NCH   30     // K-chunks of 32
#define NPH   15     // phases (2 chunks each)

// Workspace layout (float indices):
//   wf  bf16 fragment-ordered, PADDED: [NCH][8192 B] (frags in first 6144 B)
//   bias f32[96] at 61440 ; y bf16[16][96][3136] at 61568
#define WF_OFF   0
#define BIAS_OFF 61440
#define Y_OFF    61568

typedef __attribute__((ext_vector_type(8))) short bf16x8;
typedef __attribute__((ext_vector_type(4))) float f32x4;

__device__ __forceinline__ short f2b(float f) {
    union { float f; unsigned u; } c; c.f = f;
    unsigned r = (c.u + 0x7FFFu + ((c.u >> 16) & 1u)) >> 16;
    return (short)r;
}
__device__ __forceinline__ float b2f(short s) {
    union { unsigned u; float f; } c;
    c.u = ((unsigned)(unsigned short)s) << 16;
    return c.f;
}

#define GLOAD_LDS16(gp, lp)                                                        \
    __builtin_amdgcn_global_load_lds(                                              \
        (const __attribute__((address_space(1))) unsigned*)(gp),                   \
        (__attribute__((address_space(3))) unsigned*)(lp), 16, 0, 0)

// ---------------------------------------------------------------------------
// K0a: fragment-ordered weights, padded per chunk (identical to round 8).
__global__ void prep_wb(const float* __restrict__ pw, const float* __restrict__ sc,
                        short* __restrict__ wf) {
    int idx = blockIdx.x * 256 + threadIdx.x;   // (n*6+f)*64 + lane
    if (idx >= NCH * 6 * 64) return;
    const int lane = idx & 63;
    const int nf   = idx >> 6;
    const int f    = nf % 6;
    const int n    = nf / 6;
    const int o    = f * 16 + (lane & 15);
    const int c0   = n * 32 + (lane >> 4) * 8;
    bf16x8 v;
#pragma unroll
    for (int k = 0; k < 8; ++k)
        v[k] = f2b(pw[o * CIN + c0 + k] * (sc[c0 + k] + 1e-5f));
    *(bf16x8*)((char*)wf + (size_t)n * 8192 + (f * 64 + lane) * 16) = v;
}

// bias_o[o] = sum_c proj_w[o][c] * local_bias[c]
__global__ void prep_bias(const float* __restrict__ pw, const float* __restrict__ bi,
                          float* __restrict__ bias) {
    const int o = blockIdx.x;
    const int l = threadIdx.x;
    float s = 0.f;
    for (int c = l; c < CIN; c += 64) s += pw[o * CIN + c] * bi[c];
#pragma unroll
    for (int off = 32; off; off >>= 1) s += __shfl_down(s, off);
    if (l == 0) bias[o] = s;
}

// ---------------------------------------------------------------------------
// K1: y[b,o,px] = sum_c W[o][c]*x[b,c,px]   (bias added in finalize; y bf16)
// 512 thr / 8 waves (2M x 4N), 64 px x 96 out per block. 15 phases of 2
// K-chunks. Per phase per wave: 8 coalesced x-dword loads (reg), pack->bf16,
// 1 ds_write_b128 (k-contiguous x slab); 2 W gload_lds16 issued AFTER the
// barrier (so the DMA can't land on a buffer still being read); compute =
// 8 ds_read_b128 + 6 MFMA. vmcnt(8) steady / vmcnt(0) tail; lgkmcnt(0)
// before each barrier (also retires the previous compute's ds_reads --
// closes the write-after-read window on the x double buffer).
__global__ __launch_bounds__(512)
void conv_mfma(const float* __restrict__ x, const short* __restrict__ wf,
               short* __restrict__ yb) {
    const int tid  = threadIdx.x;
    const int lane = tid & 63;
    const int wv   = tid >> 6;          // 0..7
    const int m    = wv >> 2;           // o-half
    const int n    = wv & 3;            // px tile
    const int b    = blockIdx.y;
    const int px0  = blockIdx.x * 64;

    __shared__ __align__(16) char xls[2 * 8192];    // bf16 x: [2ch-sub][4kb][64px][8k]
    __shared__ __align__(16) char wls[2 * 16384];   // W: [2ch-sub][8192 B r8-format]

    const float* xbase = x + (size_t)b * CIN * PIX + px0 + lane;
    const char*  wfB   = (const char*)wf;

    // staging role: wave stages x slab (s = wv>>2, kb = wv&3) + W slot wv
    const int ssub = (wv >> 2) * 4096 + (wv & 3) * 1024 + lane * 16;  // x LDS byte
    const int sc0  = (wv >> 2) * 32 + (wv & 3) * 8;   // ch = p*64 + sc0 + k
    // compute role
    const int bbase = (lane >> 4) * 1024 + (n * 16 + (lane & 15)) * 16; // + s*4096
    const int abase = m * 3072 + lane * 16;                             // + f*1024 + s*8192

    f32x4 acc0 = {0.f, 0.f, 0.f, 0.f};
    f32x4 acc1 = {0.f, 0.f, 0.f, 0.f};
    f32x4 acc2 = {0.f, 0.f, 0.f, 0.f};

    float vA[8], vB[8];

#define XLOAD(DST, P)                                                            \
    {                                                                            \
        _Pragma("unroll")                                                        \
        for (int k = 0; k < 8; ++k)                                              \
            DST[k] = xbase[(size_t)((P) * 64 + sc0 + k) * PIX];                  \
    }
#define WLOAD(P)                                                                 \
    {                                                                            \
        _Pragma("unroll")                                                        \
        for (int s = 0; s < 2; ++s)                                              \
            GLOAD_LDS16(wfB + (size_t)(2 * (P) + s) * 8192 + wv * 1024 + lane * 16, \
                        wls + ((P) & 1) * 16384 + s * 8192 + wv * 1024);         \
    }
#define PACKWRITE(CUR, P)                                                        \
    {                                                                            \
        bf16x8 pk;                                                               \
        _Pragma("unroll")                                                        \
        for (int k = 0; k < 8; ++k) pk[k] = f2b(CUR[k]);                         \
        *(bf16x8*)(xls + ((P) & 1) * 8192 + ssub) = pk;                          \
    }
#define COMPUTE(P)                                                               \
    {                                                                            \
        _Pragma("unroll")                                                        \
        for (int s = 0; s < 2; ++s) {                                            \
            const bf16x8 bf = *(const bf16x8*)(xls + ((P) & 1) * 8192 + s * 4096 + bbase); \
            const char* wb_ = wls + ((P) & 1) * 16384 + s * 8192 + abase;        \
            const bf16x8 a0 = *(const bf16x8*)(wb_);                             \
            const bf16x8 a1 = *(const bf16x8*)(wb_ + 1024);                      \
            const bf16x8 a2 = *(const bf16x8*)(wb_ + 2048);                      \
            acc0 = __builtin_amdgcn_mfma_f32_16x16x32_bf16(a0, bf, acc0, 0,0,0); \
            acc1 = __builtin_amdgcn_mfma_f32_16x16x32_bf16(a1, bf, acc1, 0,0,0); \
            acc2 = __builtin_amdgcn_mfma_f32_16x16x32_bf16(a2, bf, acc2, 0,0,0); \
        }                                                                        \
    }
// PHASE: [issue x(P+1)] wait x(P)&W(P) -> pack/write x(P) -> lgkm+barrier ->
//        [issue W(P+1) DMA -- safe: all waves' reads of that buffer retired]
//        -> compute(P)
#define PHASE(P, CUR, NXT, VM, ISSUE)                                            \
    {                                                                            \
        if (ISSUE) XLOAD(NXT, (P) + 1);                                          \
        asm volatile("s_waitcnt vmcnt(" #VM ")" ::: "memory");                   \
        PACKWRITE(CUR, P);                                                       \
        asm volatile("s_waitcnt lgkmcnt(0)" ::: "memory");                       \
        asm volatile("s_barrier" ::: "memory");                                  \
        if (ISSUE) WLOAD((P) + 1);                                               \
        COMPUTE(P);                                                              \
    }

    // prologue: x(0) regs + W(0) DMA in flight
    XLOAD(vA, 0);
    WLOAD(0);

#pragma unroll 1
    for (int pp = 0; pp < 7; ++pp) {
        const int p0 = pp * 2;
        PHASE(p0 + 0, vA, vB, 8, 1);
        PHASE(p0 + 1, vB, vA, 8, 1);
    }
    PHASE(14, vA, vB, 0, 0);   // tail: drain everything
#undef PHASE
#undef COMPUTE
#undef PACKWRITE
#undef WLOAD
#undef XLOAD

    // epilogue: C/D col(px) = lane&15, row(o) = (lane>>4)*4 + r
    short* yp = yb + (size_t)b * COUT * PIX + px0 + n * 16 + (lane & 15);
    const int o0 = m * 48 + (lane >> 4) * 4;
#pragma unroll
    for (int r = 0; r < 4; ++r) yp[(size_t)(o0 +      r) * PIX] = f2b(acc0[r]);
#pragma unroll
    for (int r = 0; r < 4; ++r) yp[(size_t)(o0 + 16 + r) * PIX] = f2b(acc1[r]);
#pragma unroll
    for (int r = 0; r < 4; ++r) yp[(size_t)(o0 + 32 + r) * PIX] = f2b(acc2[r]);
}

// ---------------------------------------------------------------------------
// Antialiased 58->56 triangle weights; tap indices mapped to the 56-grid.
__device__ __forceinline__ void rweights56(int o, short* idx, float* wt) {
    const float ratio = 58.0f / 56.0f;
    const float kinv  = 56.0f / 58.0f;
    const float sf = ((float)o + 0.5f) * ratio - 0.5f;
    const int f0 = (int)floorf(sf);
    float sum = 0.f;
#pragma unroll
    for (int t = 0; t < 4; ++t) {
        int i = f0 - 1 + t;
        float w = fmaxf(1.0f - fabsf(sf - (float)i) * kinv, 0.0f);
        if (i < 0 || i > 57) w = 0.0f;
        idx[t] = (short)min(HH - 1, max(0, i - 1));
        wt[t] = w;
        sum += w;
    }
    const float inv = 1.0f / sum;
#pragma unroll
    for (int t = 0; t < 4; ++t) wt[t] *= inv;
}

// ---------------------------------------------------------------------------
// K2: identical to round 8 (passing, ~35 us).
__global__ __launch_bounds__(256)
void finalize(const float* __restrict__ x, const int* __restrict__ pad_hv,
              const int* __restrict__ idt, const short* __restrict__ yb,
              const float* __restrict__ bias, const float* __restrict__ alpha_p,
              float* __restrict__ out) {
    const int bc = blockIdx.x;          // b*96 + co
    const int co = bc % COUT;
    const int b  = bc / COUT;
    const int t  = threadIdx.x;

    __shared__ float  ylds[PIX];
    __shared__ float4 wt4[56];
    __shared__ short4 id4[56];
    __shared__ int   ish[10], isv[10], ipl[10];
    __shared__ float fid[10];

    if (t < 10) {
        const int g = t / 5;
        const int k = t - g * 5;
        const int slot = co * NK_ + k;
        ish[t] = pad_hv[slot * 4 + g];
        isv[t] = pad_hv[slot * 4 + 2 + g];
        fid[t] = (idt[slot * 2 + g] >= 0) ? 1.f : 0.f;
        ipl[t] = (g * (COUT * NK_) + slot) * PIX;
    }
    if (t < 56) {
        short ii[4]; float ww[4];
        rweights56(t, ii, ww);
        wt4[t] = make_float4(ww[0], ww[1], ww[2], ww[3]);
        id4[t] = make_short4(ii[0], ii[1], ii[2], ii[3]);
    }
    {
        const short* yp = yb + (size_t)bc * PIX;
#pragma unroll 1
        for (int i = t; i < PIX / 4; i += 256) {
            const short4 s4 = *(const short4*)(yp + i * 4);
            *(float4*)(ylds + i * 4) =
                make_float4(b2f(s4.x), b2f(s4.y), b2f(s4.z), b2f(s4.w));
        }
    }
    __syncthreads();

    int   ish_r[10], isv_r[10], ipl_r[10];
    float fid_r[10];
#pragma unroll
    for (int p = 0; p < 10; ++p) {
        ish_r[p] = ish[p]; isv_r[p] = isv[p];
        ipl_r[p] = ipl[p]; fid_r[p] = fid[p];
    }

    const float alpha = alpha_p[0];
    const float ia    = 1.0f - alpha;
    const float bco   = bias[co];
    const float* xb = x + (size_t)b * CIN * PIX;
    float* op = out + (size_t)bc * PIX;

#pragma unroll 1
    for (int px = t; px < PIX; px += 256) {
        const int h = (px * 18725) >> 20;
        const int w = px - h * WW_;
        const int hrow = px - w;

        float accg = 0.f;
#pragma unroll
        for (int p = 0; p < 10; ++p) {
            const float* xc = xb + ipl_r[p];
            const int jw = w + ish_r[p];
            const float mh = (jw >= -1 && jw <= WW_) ? 1.f : 0.f;
            accg += mh * xc[hrow + min(WW_ - 1, max(0, jw))];

            const int iv = h + isv_r[p];
            const float mv = (iv >= -1 && iv <= HH) ? 1.f : 0.f;
            accg += mv * xc[min(HH - 1, max(0, iv)) * WW_ + w];

            accg += fid_r[p] * xc[px];
        }

        const float4 ww4 = wt4[w];
        const short4 iw4 = id4[w];
        const float4 wh4 = wt4[h];
        const short4 ih4 = id4[h];
        float accl = 0.f;
#pragma unroll
        for (int a = 0; a < 4; ++a) {
            const int row = ((const short*)&ih4)[a] * WW_;
            const float* yr = ylds + row;
            float rs;
            rs = ww4.x * yr[iw4.x];
            rs = fmaf(ww4.y, yr[iw4.y], rs);
            rs = fmaf(ww4.z, yr[iw4.z], rs);
            rs = fmaf(ww4.w, yr[iw4.w], rs);
            accl = fmaf(((const float*)&wh4)[a], rs, accl);
        }
        accl += bco;

        op[px] = alpha * accg * (1.0f / 3.0f) + ia * accl;
    }
}

// ---------------------------------------------------------------------------
extern "C" void kernel_launch(void* const* d_in, const int* in_sizes, int n_in,
                              void* d_out, int out_size, void* d_ws, size_t ws_size,
                              hipStream_t stream) {
    const float* x      = (const float*)d_in[0];
    const int*   pad_hv = (const int*)d_in[1];
    const int*   idt    = (const int*)d_in[2];
    const float* lsc    = (const float*)d_in[3];
    const float* lbi    = (const float*)d_in[4];
    const float* pw     = (const float*)d_in[5];
    const float* alpha  = (const float*)d_in[6];
    float* out = (float*)d_out;

    float* ws   = (float*)d_ws;
    short* wf   = (short*)(ws + WF_OFF);
    float* bias = ws + BIAS_OFF;
    short* yb   = (short*)(ws + Y_OFF);

    prep_wb<<<(NCH * 6 * 64 + 255) / 256, 256, 0, stream>>>(pw, lsc, wf);
    prep_bias<<<COUT, 64, 0, stream>>>(pw, lbi, bias);
    conv_mfma<<<dim3(PIX / 64, B_), 512, 0, stream>>>(x, wf, yb);
    finalize<<<B_ * COUT, 256, 0, stream>>>(x, pad_hv, idt, yb, bias, alpha, out);
}

// Round 10
// 99.839 us; speedup vs baseline: 1.0231x; 1.0231x over previous
//
#include <hip/hip_runtime.h>
#include <hip/hip_bf16.h>
#include <cstdint>
#include <cstddef>

// Problem constants
#define B_    16
#define CIN   960
#define HH    56
#define WW_   56
#define GG    2
#define COUT  96
#define NK_   5
#define PIX   3136   // 56*56
#define NCH   30     // K-chunks of 32

// Workspace layout (float indices):
//   wf  bf16 fragment-ordered, PADDED: [NCH][8192 B] (frags in first 6144 B)
//   bias f32[96] at 61440 ; y bf16[16][96][3136] at 61568
#define WF_OFF   0
#define BIAS_OFF 61440
#define Y_OFF    61568

typedef __attribute__((ext_vector_type(8))) short bf16x8;
typedef __attribute__((ext_vector_type(4))) float f32x4;

__device__ __forceinline__ short f2b(float f) {
    union { float f; unsigned u; } c; c.f = f;
    unsigned r = (c.u + 0x7FFFu + ((c.u >> 16) & 1u)) >> 16;
    return (short)r;
}
__device__ __forceinline__ float b2f(short s) {
    union { unsigned u; float f; } c;
    c.u = ((unsigned)(unsigned short)s) << 16;
    return c.f;
}

#define GLOAD_LDS16(gp, lp)                                                        \
    __builtin_amdgcn_global_load_lds(                                              \
        (const __attribute__((address_space(1))) unsigned*)(gp),                   \
        (__attribute__((address_space(3))) unsigned*)(lp), 16, 0, 0)

// ---------------------------------------------------------------------------
// K0a: fragment-ordered weights, padded per chunk (identical to 93.5 build).
__global__ void prep_wb(const float* __restrict__ pw, const float* __restrict__ sc,
                        short* __restrict__ wf) {
    int idx = blockIdx.x * 256 + threadIdx.x;   // (n*6+f)*64 + lane
    if (idx >= NCH * 6 * 64) return;
    const int lane = idx & 63;
    const int nf   = idx >> 6;
    const int f    = nf % 6;
    const int n    = nf / 6;
    const int o    = f * 16 + (lane & 15);
    const int c0   = n * 32 + (lane >> 4) * 8;
    bf16x8 v;
#pragma unroll
    for (int k = 0; k < 8; ++k)
        v[k] = f2b(pw[o * CIN + c0 + k] * (sc[c0 + k] + 1e-5f));
    *(bf16x8*)((char*)wf + (size_t)n * 8192 + (f * 64 + lane) * 16) = v;
}

// bias_o[o] = sum_c proj_w[o][c] * local_bias[c]   (96 blocks x 1 wave)
__global__ void prep_bias(const float* __restrict__ pw, const float* __restrict__ bi,
                          float* __restrict__ bias) {
    const int o = blockIdx.x;
    const int l = threadIdx.x;
    float s = 0.f;
    for (int c = l; c < CIN; c += 64) s += pw[o * CIN + c] * bi[c];
#pragma unroll
    for (int off = 32; off; off >>= 1) s += __shfl_down(s, off);
    if (l == 0) bias[o] = s;
}

// ---------------------------------------------------------------------------
// K1: y[b,o,px] = sum_c W[o][c]*x[b,c,px]  -- EXACT 93.5-us build (round 8).
// 512 thr / 8 waves (2M x 4N); 3-buffer LDS pipeline, raw s_barrier,
// counted vmcnt(2), distance-2 DMA prefetch (x gload_lds16 + W gload_lds16).
__global__ __launch_bounds__(512)
void conv_mfma(const float* __restrict__ x, const short* __restrict__ wf,
               short* __restrict__ yb) {
    const int tid  = threadIdx.x;
    const int lane = tid & 63;
    const int wv   = tid >> 6;          // 0..7
    const int m    = wv >> 2;           // o-half
    const int n    = wv & 3;            // px tile
    const int b    = blockIdx.y;
    const int px0  = blockIdx.x * 64;

    __shared__ __align__(16) char xsb[3 * 8192];   // x chunks [32ch][64px] f32
    __shared__ __align__(16) char wlb[3 * 8192];   // W chunks (6 frags + pad)

    const float* xbase = x + (size_t)b * CIN * PIX + px0;
    const char*  wfB   = (const char*)wf;

    // staging constants (one x-DMA + one W-DMA per wave per chunk)
    const int sch  = wv * 4 + (lane >> 4);               // channel within chunk
    const int sS   = (wv >> 1) & 3;                      // == (sch>>3)&3
    const int soff = (((lane >> 2) & 3) ^ sS) * 16 + (lane & 3) * 4;  // src px (floats)
    const int wsub = wv * 1024 + lane * 16;              // W copy offset (bytes)

    // compute constants
    const int kb    = lane >> 4;
    const int bcol  = (lane & 15) * 4;
    const int bslot = ((n ^ kb) & 3) * 64;
    const int babs  = kb * 2048 + bslot + bcol;          // + k*256, + BI*8192
    const int abase = m * 3072 + lane * 16;              // + fl*1024, + BI*8192

    f32x4 acc0 = {0.f, 0.f, 0.f, 0.f};
    f32x4 acc1 = {0.f, 0.f, 0.f, 0.f};
    f32x4 acc2 = {0.f, 0.f, 0.f, 0.f};

#define STAGE(BS, c0)                                                            \
    {                                                                            \
        GLOAD_LDS16(xbase + (size_t)((c0) + sch) * PIX + soff,                   \
                    xsb + (BS) * 8192 + wv * 1024);                              \
        GLOAD_LDS16(wfB + (size_t)((c0) >> 5) * 8192 + wsub,                     \
                    wlb + (BS) * 8192 + wv * 1024);                              \
    }

    // prologue: chunks 0,1 in flight (4 VMEM/wave)
    STAGE(0, 0);
    STAGE(1, 32);

#define STEP(n_, BI, BS, VM)                                                     \
    {                                                                            \
        asm volatile("s_waitcnt vmcnt(" #VM ")" ::: "memory");                   \
        asm volatile("s_barrier" ::: "memory");                                  \
        bf16x8 bfrag;                                                            \
        _Pragma("unroll")                                                        \
        for (int k = 0; k < 8; ++k)                                              \
            bfrag[k] = f2b(*(const float*)(xsb + (BI) * 8192 + babs + k * 256)); \
        const bf16x8 af0 = *(const bf16x8*)(wlb + (BI) * 8192 + abase);          \
        const bf16x8 af1 = *(const bf16x8*)(wlb + (BI) * 8192 + abase + 1024);   \
        const bf16x8 af2 = *(const bf16x8*)(wlb + (BI) * 8192 + abase + 2048);   \
        if ((n_) + 2 < NCH) STAGE(BS, ((n_) + 2) * 32);                          \
        acc0 = __builtin_amdgcn_mfma_f32_16x16x32_bf16(af0, bfrag, acc0, 0,0,0); \
        acc1 = __builtin_amdgcn_mfma_f32_16x16x32_bf16(af1, bfrag, acc1, 0,0,0); \
        acc2 = __builtin_amdgcn_mfma_f32_16x16x32_bf16(af2, bfrag, acc2, 0,0,0); \
    }

#pragma unroll 1
    for (int mm = 0; mm < 9; ++mm) {
        const int n0 = mm * 3;
        STEP(n0 + 0, 0, 2, 2);
        STEP(n0 + 1, 1, 0, 2);
        STEP(n0 + 2, 2, 1, 2);
    }
    STEP(27, 0, 2, 2);
    STEP(28, 1, 0, 2);
    STEP(29, 2, 1, 0);   // drain: the tail chunk must actually land
#undef STEP
#undef STAGE

    // epilogue: C/D col(px) = lane&15, row(o) = (lane>>4)*4 + r
    short* yp = yb + (size_t)b * COUT * PIX + px0 + n * 16 + (lane & 15);
    const int o0 = m * 48 + (lane >> 4) * 4;
#pragma unroll
    for (int r = 0; r < 4; ++r) yp[(size_t)(o0 +      r) * PIX] = f2b(acc0[r]);
#pragma unroll
    for (int r = 0; r < 4; ++r) yp[(size_t)(o0 + 16 + r) * PIX] = f2b(acc1[r]);
#pragma unroll
    for (int r = 0; r < 4; ++r) yp[(size_t)(o0 + 32 + r) * PIX] = f2b(acc2[r]);
}

// ---------------------------------------------------------------------------
// Antialiased 58->56 triangle weights; tap indices mapped to the 56-grid.
__device__ __forceinline__ void rweights56(int o, short* idx, float* wt) {
    const float ratio = 58.0f / 56.0f;
    const float kinv  = 56.0f / 58.0f;
    const float sf = ((float)o + 0.5f) * ratio - 0.5f;
    const int f0 = (int)floorf(sf);
    float sum = 0.f;
#pragma unroll
    for (int t = 0; t < 4; ++t) {
        int i = f0 - 1 + t;
        float w = fmaxf(1.0f - fabsf(sf - (float)i) * kinv, 0.0f);
        if (i < 0 || i > 57) w = 0.0f;
        idx[t] = (short)min(HH - 1, max(0, i - 1));
        wt[t] = w;
        sum += w;
    }
    const float inv = 1.0f / sum;
#pragma unroll
    for (int t = 0; t < 4; ++t) wt[t] *= inv;
}

// ---------------------------------------------------------------------------
// K2: one block per (b,co) plane, 256 thr, 2 px/thread (w even -> w,w+1 in
// the same row). v-shift and identity taps are float2 (8B-aligned); h-shift
// taps stay scalar x2. y plane staged bf16->f32 in LDS; resize tables in LDS.
__global__ __launch_bounds__(256)
void finalize(const float* __restrict__ x, const int* __restrict__ pad_hv,
              const int* __restrict__ idt, const short* __restrict__ yb,
              const float* __restrict__ bias, const float* __restrict__ alpha_p,
              float* __restrict__ out) {
    const int bc = blockIdx.x;          // b*96 + co
    const int co = bc % COUT;
    const int b  = bc / COUT;
    const int t  = threadIdx.x;

    __shared__ float  ylds[PIX];        // 12544 B
    __shared__ float4 wt4[56];
    __shared__ short4 id4[56];
    __shared__ int   ish[10], isv[10], ipl[10];
    __shared__ float fid[10];

    if (t < 10) {
        const int g = t / 5;
        const int k = t - g * 5;
        const int slot = co * NK_ + k;
        ish[t] = pad_hv[slot * 4 + g];
        isv[t] = pad_hv[slot * 4 + 2 + g];
        fid[t] = (idt[slot * 2 + g] >= 0) ? 1.f : 0.f;
        ipl[t] = (g * (COUT * NK_) + slot) * PIX;
    }
    if (t < 56) {
        short ii[4]; float ww[4];
        rweights56(t, ii, ww);
        wt4[t] = make_float4(ww[0], ww[1], ww[2], ww[3]);
        id4[t] = make_short4(ii[0], ii[1], ii[2], ii[3]);
    }
    {   // stage y plane as f32
        const short* yp = yb + (size_t)bc * PIX;
#pragma unroll 1
        for (int i = t; i < PIX / 4; i += 256) {
            const short4 s4 = *(const short4*)(yp + i * 4);
            *(float4*)(ylds + i * 4) =
                make_float4(b2f(s4.x), b2f(s4.y), b2f(s4.z), b2f(s4.w));
        }
    }
    __syncthreads();

    int   ish_r[10], isv_r[10], ipl_r[10];
    float fid_r[10];
#pragma unroll
    for (int p = 0; p < 10; ++p) {
        ish_r[p] = ish[p]; isv_r[p] = isv[p];
        ipl_r[p] = ipl[p]; fid_r[p] = fid[p];
    }

    const float alpha = alpha_p[0];
    const float ia    = 1.0f - alpha;
    const float bco   = bias[co];
    const float* xb = x + (size_t)b * CIN * PIX;
    float* op = out + (size_t)bc * PIX;

#pragma unroll 1
    for (int pp = t; pp < PIX / 2; pp += 256) {
        const int p2 = pp * 2;                  // even pixel; p2+1 same row
        const int h = (p2 * 18725) >> 20;       // p2/56
        const int w = p2 - h * WW_;             // even
        const int hrow = p2 - w;                // h*56

        float a0 = 0.f, a1 = 0.f;
#pragma unroll
        for (int p = 0; p < 10; ++p) {
            const float* xc = xb + ipl_r[p];

            // horizontal shift: two scalar taps (clamps may differ)
            const int jw = w + ish_r[p];
            const float m0 = (jw >= -1 && jw <= WW_) ? 1.f : 0.f;
            const float m1 = (jw >= -2 && jw <= WW_ - 1) ? 1.f : 0.f;
            a0 += m0 * xc[hrow + min(WW_ - 1, max(0, jw))];
            a1 += m1 * xc[hrow + min(WW_ - 1, max(0, jw + 1))];

            // vertical shift: same clamped row for both px -> float2
            const int iv = h + isv_r[p];
            const float mv = (iv >= -1 && iv <= HH) ? 1.f : 0.f;
            const float2 vv = *(const float2*)(xc + min(HH - 1, max(0, iv)) * WW_ + w);
            a0 += mv * vv.x;
            a1 += mv * vv.y;

            // identity: float2
            const float2 iv2 = *(const float2*)(xc + hrow + w);
            a0 += fid_r[p] * iv2.x;
            a1 += fid_r[p] * iv2.y;
        }

        // separable antialiased resize from LDS (h rows shared by both px)
        const float4 wha = wt4[h];
        const short4 iha = id4[h];
        const float4 wwa = wt4[w];
        const short4 iwa = id4[w];
        const float4 wwb = wt4[w + 1];
        const short4 iwb = id4[w + 1];
        float l0 = 0.f, l1 = 0.f;
#pragma unroll
        for (int a = 0; a < 4; ++a) {
            const float* yr = ylds + ((const short*)&iha)[a] * WW_;
            float r0, r1;
            r0 = wwa.x * yr[iwa.x];
            r1 = wwb.x * yr[iwb.x];
            r0 = fmaf(wwa.y, yr[iwa.y], r0);
            r1 = fmaf(wwb.y, yr[iwb.y], r1);
            r0 = fmaf(wwa.z, yr[iwa.z], r0);
            r1 = fmaf(wwb.z, yr[iwb.z], r1);
            r0 = fmaf(wwa.w, yr[iwa.w], r0);
            r1 = fmaf(wwb.w, yr[iwb.w], r1);
            const float wh = ((const float*)&wha)[a];
            l0 = fmaf(wh, r0, l0);
            l1 = fmaf(wh, r1, l1);
        }

        float2 res;
        res.x = alpha * a0 * (1.0f / 3.0f) + ia * (l0 + bco);
        res.y = alpha * a1 * (1.0f / 3.0f) + ia * (l1 + bco);
        *(float2*)(op + p2) = res;
    }
}

// ---------------------------------------------------------------------------
extern "C" void kernel_launch(void* const* d_in, const int* in_sizes, int n_in,
                              void* d_out, int out_size, void* d_ws, size_t ws_size,
                              hipStream_t stream) {
    const float* x      = (const float*)d_in[0];
    const int*   pad_hv = (const int*)d_in[1];
    const int*   idt    = (const int*)d_in[2];
    const float* lsc    = (const float*)d_in[3];
    const float* lbi    = (const float*)d_in[4];
    const float* pw     = (const float*)d_in[5];
    const float* alpha  = (const float*)d_in[6];
    float* out = (float*)d_out;

    float* ws   = (float*)d_ws;
    short* wf   = (short*)(ws + WF_OFF);
    float* bias = ws + BIAS_OFF;
    short* yb   = (short*)(ws + Y_OFF);

    prep_wb<<<(NCH * 6 * 64 + 255) / 256, 256, 0, stream>>>(pw, lsc, wf);
    prep_bias<<<COUT, 64, 0, stream>>>(pw, lbi, bias);
    conv_mfma<<<dim3(PIX / 64, B_), 512, 0, stream>>>(x, wf, yb);
    finalize<<<B_ * COUT, 256, 0, stream>>>(x, pad_hv, idt, yb, bias, alpha, out);
}

// Round 11
// 95.359 us; speedup vs baseline: 1.0712x; 1.0470x over previous
//
#include <hip/hip_runtime.h>
#include <hip/hip_bf16.h>
#include <cstdint>
#include <cstddef>

// Problem constants
#define B_    16
#define CIN   960
#define HH    56
#define WW_   56
#define GG    2
#define COUT  96
#define NK_   5
#define PIX   3136   // 56*56
#define NCH   30     // K-chunks of 32

// Workspace layout (float indices):
//   wf  bf16 fragment-ordered, PADDED: [NCH][8192 B] (frags in first 6144 B)
//   bias f32[96] at 61440 ; y bf16[16][96][3136] at 61568
#define WF_OFF   0
#define BIAS_OFF 61440
#define Y_OFF    61568

typedef __attribute__((ext_vector_type(8))) short bf16x8;
typedef __attribute__((ext_vector_type(4))) float f32x4;

__device__ __forceinline__ short f2b(float f) {
    union { float f; unsigned u; } c; c.f = f;
    unsigned r = (c.u + 0x7FFFu + ((c.u >> 16) & 1u)) >> 16;
    return (short)r;
}
__device__ __forceinline__ float b2f(short s) {
    union { unsigned u; float f; } c;
    c.u = ((unsigned)(unsigned short)s) << 16;
    return c.f;
}

#define GLOAD_LDS16(gp, lp)                                                        \
    __builtin_amdgcn_global_load_lds(                                              \
        (const __attribute__((address_space(1))) unsigned*)(gp),                   \
        (__attribute__((address_space(3))) unsigned*)(lp), 16, 0, 0)

// ---------------------------------------------------------------------------
// K0a: fragment-ordered weights, padded per chunk (identical to 93.5 build).
__global__ void prep_wb(const float* __restrict__ pw, const float* __restrict__ sc,
                        short* __restrict__ wf) {
    int idx = blockIdx.x * 256 + threadIdx.x;   // (n*6+f)*64 + lane
    if (idx >= NCH * 6 * 64) return;
    const int lane = idx & 63;
    const int nf   = idx >> 6;
    const int f    = nf % 6;
    const int n    = nf / 6;
    const int o    = f * 16 + (lane & 15);
    const int c0   = n * 32 + (lane >> 4) * 8;
    bf16x8 v;
#pragma unroll
    for (int k = 0; k < 8; ++k)
        v[k] = f2b(pw[o * CIN + c0 + k] * (sc[c0 + k] + 1e-5f));
    *(bf16x8*)((char*)wf + (size_t)n * 8192 + (f * 64 + lane) * 16) = v;
}

// bias_o[o] = sum_c proj_w[o][c] * local_bias[c]   (96 blocks x 1 wave)
__global__ void prep_bias(const float* __restrict__ pw, const float* __restrict__ bi,
                          float* __restrict__ bias) {
    const int o = blockIdx.x;
    const int l = threadIdx.x;
    float s = 0.f;
    for (int c = l; c < CIN; c += 64) s += pw[o * CIN + c] * bi[c];
#pragma unroll
    for (int off = 32; off; off >>= 1) s += __shfl_down(s, off);
    if (l == 0) bias[o] = s;
}

// ---------------------------------------------------------------------------
// K1: y[b,o,px] = sum_c W[o][c]*x[b,c,px]  (bias in finalize; y bf16)
// 512 thr / 8 waves (2M x 4N), 64 px x 96 out per block.
// 4-buffer LDS pipeline, raw s_barrier, prefetch DISTANCE 3:
//   STEP(n): wait vmcnt(4) [retires chunk n; n+1,n+2 stay in flight],
//   barrier, frag reads, STAGE(n+3), 3 MFMA.  Tail: vmcnt(2), vmcnt(0).
// Cover = 3 step-walls (~>HBM latency). LDS 64 KB -> 2 blocks/CU; in-flight
// bytes per CU unchanged vs 3-buffer/3-block build (Little's law neutral).
__global__ __launch_bounds__(512)
void conv_mfma(const float* __restrict__ x, const short* __restrict__ wf,
               short* __restrict__ yb) {
    const int tid  = threadIdx.x;
    const int lane = tid & 63;
    const int wv   = tid >> 6;          // 0..7
    const int m    = wv >> 2;           // o-half
    const int n    = wv & 3;            // px tile
    const int b    = blockIdx.y;
    const int px0  = blockIdx.x * 64;

    __shared__ __align__(16) char xsb[4 * 8192];   // x chunks [32ch][64px] f32
    __shared__ __align__(16) char wlb[4 * 8192];   // W chunks (6 frags + pad)

    const float* xbase = x + (size_t)b * CIN * PIX + px0;
    const char*  wfB   = (const char*)wf;

    // staging constants (one x-DMA + one W-DMA per wave per chunk)
    const int sch  = wv * 4 + (lane >> 4);               // channel within chunk
    const int sS   = (wv >> 1) & 3;                      // == (sch>>3)&3
    const int soff = (((lane >> 2) & 3) ^ sS) * 16 + (lane & 3) * 4;  // src px (floats)
    const int wsub = wv * 1024 + lane * 16;              // W copy offset (bytes)

    // compute constants
    const int kb    = lane >> 4;
    const int bcol  = (lane & 15) * 4;
    const int bslot = ((n ^ kb) & 3) * 64;
    const int babs  = kb * 2048 + bslot + bcol;          // + k*256, + BI*8192
    const int abase = m * 3072 + lane * 16;              // + fl*1024, + BI*8192

    f32x4 acc0 = {0.f, 0.f, 0.f, 0.f};
    f32x4 acc1 = {0.f, 0.f, 0.f, 0.f};
    f32x4 acc2 = {0.f, 0.f, 0.f, 0.f};

#define STAGE(BS, c0)                                                            \
    {                                                                            \
        GLOAD_LDS16(xbase + (size_t)((c0) + sch) * PIX + soff,                   \
                    xsb + (BS) * 8192 + wv * 1024);                              \
        GLOAD_LDS16(wfB + (size_t)((c0) >> 5) * 8192 + wsub,                     \
                    wlb + (BS) * 8192 + wv * 1024);                              \
    }

    // prologue: chunks 0,1,2 in flight (6 VMEM/wave)
    STAGE(0, 0);
    STAGE(1, 32);
    STAGE(2, 64);

#define STEP(n_, BI, BS, VM)                                                     \
    {                                                                            \
        asm volatile("s_waitcnt vmcnt(" #VM ")" ::: "memory");                   \
        asm volatile("s_barrier" ::: "memory");                                  \
        bf16x8 bfrag;                                                            \
        _Pragma("unroll")                                                        \
        for (int k = 0; k < 8; ++k)                                              \
            bfrag[k] = f2b(*(const float*)(xsb + (BI) * 8192 + babs + k * 256)); \
        const bf16x8 af0 = *(const bf16x8*)(wlb + (BI) * 8192 + abase);          \
        const bf16x8 af1 = *(const bf16x8*)(wlb + (BI) * 8192 + abase + 1024);   \
        const bf16x8 af2 = *(const bf16x8*)(wlb + (BI) * 8192 + abase + 2048);   \
        if ((n_) + 3 < NCH) STAGE(BS, ((n_) + 3) * 32);                          \
        acc0 = __builtin_amdgcn_mfma_f32_16x16x32_bf16(af0, bfrag, acc0, 0,0,0); \
        acc1 = __builtin_amdgcn_mfma_f32_16x16x32_bf16(af1, bfrag, acc1, 0,0,0); \
        acc2 = __builtin_amdgcn_mfma_f32_16x16x32_bf16(af2, bfrag, acc2, 0,0,0); \
    }

    // steps 0..27: steady state (wait retires chunk n; issues chunk n+3)
#pragma unroll 1
    for (int mm = 0; mm < 7; ++mm) {
        const int n0 = mm * 4;
        STEP(n0 + 0, 0, 3, 4);
        STEP(n0 + 1, 1, 0, 4);
        STEP(n0 + 2, 2, 1, 4);
        STEP(n0 + 3, 3, 2, 4);
    }
    // tail: outstanding after step 27 = chunks 28,29 (4 loads)
    STEP(28, 0, 0, 2);
    STEP(29, 1, 0, 0);
#undef STEP
#undef STAGE

    // epilogue: C/D col(px) = lane&15, row(o) = (lane>>4)*4 + r
    short* yp = yb + (size_t)b * COUT * PIX + px0 + n * 16 + (lane & 15);
    const int o0 = m * 48 + (lane >> 4) * 4;
#pragma unroll
    for (int r = 0; r < 4; ++r) yp[(size_t)(o0 +      r) * PIX] = f2b(acc0[r]);
#pragma unroll
    for (int r = 0; r < 4; ++r) yp[(size_t)(o0 + 16 + r) * PIX] = f2b(acc1[r]);
#pragma unroll
    for (int r = 0; r < 4; ++r) yp[(size_t)(o0 + 32 + r) * PIX] = f2b(acc2[r]);
}

// ---------------------------------------------------------------------------
// Antialiased 58->56 triangle weights; tap indices mapped to the 56-grid.
__device__ __forceinline__ void rweights56(int o, short* idx, float* wt) {
    const float ratio = 58.0f / 56.0f;
    const float kinv  = 56.0f / 58.0f;
    const float sf = ((float)o + 0.5f) * ratio - 0.5f;
    const int f0 = (int)floorf(sf);
    float sum = 0.f;
#pragma unroll
    for (int t = 0; t < 4; ++t) {
        int i = f0 - 1 + t;
        float w = fmaxf(1.0f - fabsf(sf - (float)i) * kinv, 0.0f);
        if (i < 0 || i > 57) w = 0.0f;
        idx[t] = (short)min(HH - 1, max(0, i - 1));
        wt[t] = w;
        sum += w;
    }
    const float inv = 1.0f / sum;
#pragma unroll
    for (int t = 0; t < 4; ++t) wt[t] *= inv;
}

// ---------------------------------------------------------------------------
// K2: EXACT round-8 finalize (1 px/thread; proven 93.5 total).
__global__ __launch_bounds__(256)
void finalize(const float* __restrict__ x, const int* __restrict__ pad_hv,
              const int* __restrict__ idt, const short* __restrict__ yb,
              const float* __restrict__ bias, const float* __restrict__ alpha_p,
              float* __restrict__ out) {
    const int bc = blockIdx.x;          // b*96 + co
    const int co = bc % COUT;
    const int b  = bc / COUT;
    const int t  = threadIdx.x;

    __shared__ float  ylds[PIX];
    __shared__ float4 wt4[56];
    __shared__ short4 id4[56];
    __shared__ int   ish[10], isv[10], ipl[10];
    __shared__ float fid[10];

    if (t < 10) {
        const int g = t / 5;
        const int k = t - g * 5;
        const int slot = co * NK_ + k;
        ish[t] = pad_hv[slot * 4 + g];
        isv[t] = pad_hv[slot * 4 + 2 + g];
        fid[t] = (idt[slot * 2 + g] >= 0) ? 1.f : 0.f;
        ipl[t] = (g * (COUT * NK_) + slot) * PIX;
    }
    if (t < 56) {
        short ii[4]; float ww[4];
        rweights56(t, ii, ww);
        wt4[t] = make_float4(ww[0], ww[1], ww[2], ww[3]);
        id4[t] = make_short4(ii[0], ii[1], ii[2], ii[3]);
    }
    {
        const short* yp = yb + (size_t)bc * PIX;
#pragma unroll 1
        for (int i = t; i < PIX / 4; i += 256) {
            const short4 s4 = *(const short4*)(yp + i * 4);
            *(float4*)(ylds + i * 4) =
                make_float4(b2f(s4.x), b2f(s4.y), b2f(s4.z), b2f(s4.w));
        }
    }
    __syncthreads();

    int   ish_r[10], isv_r[10], ipl_r[10];
    float fid_r[10];
#pragma unroll
    for (int p = 0; p < 10; ++p) {
        ish_r[p] = ish[p]; isv_r[p] = isv[p];
        ipl_r[p] = ipl[p]; fid_r[p] = fid[p];
    }

    const float alpha = alpha_p[0];
    const float ia    = 1.0f - alpha;
    const float bco   = bias[co];
    const float* xb = x + (size_t)b * CIN * PIX;
    float* op = out + (size_t)bc * PIX;

#pragma unroll 1
    for (int px = t; px < PIX; px += 256) {
        const int h = (px * 18725) >> 20;
        const int w = px - h * WW_;
        const int hrow = px - w;

        float accg = 0.f;
#pragma unroll
        for (int p = 0; p < 10; ++p) {
            const float* xc = xb + ipl_r[p];
            const int jw = w + ish_r[p];
            const float mh = (jw >= -1 && jw <= WW_) ? 1.f : 0.f;
            accg += mh * xc[hrow + min(WW_ - 1, max(0, jw))];

            const int iv = h + isv_r[p];
            const float mv = (iv >= -1 && iv <= HH) ? 1.f : 0.f;
            accg += mv * xc[min(HH - 1, max(0, iv)) * WW_ + w];

            accg += fid_r[p] * xc[px];
        }

        const float4 ww4 = wt4[w];
        const short4 iw4 = id4[w];
        const float4 wh4 = wt4[h];
        const short4 ih4 = id4[h];
        float accl = 0.f;
#pragma unroll
        for (int a = 0; a < 4; ++a) {
            const int row = ((const short*)&ih4)[a] * WW_;
            const float* yr = ylds + row;
            float rs;
            rs = ww4.x * yr[iw4.x];
            rs = fmaf(ww4.y, yr[iw4.y], rs);
            rs = fmaf(ww4.z, yr[iw4.z], rs);
            rs = fmaf(ww4.w, yr[iw4.w], rs);
            accl = fmaf(((const float*)&wh4)[a], rs, accl);
        }
        accl += bco;

        op[px] = alpha * accg * (1.0f / 3.0f) + ia * accl;
    }
}

// ---------------------------------------------------------------------------
extern "C" void kernel_launch(void* const* d_in, const int* in_sizes, int n_in,
                              void* d_out, int out_size, void* d_ws, size_t ws_size,
                              hipStream_t stream) {
    const float* x      = (const float*)d_in[0];
    const int*   pad_hv = (const int*)d_in[1];
    const int*   idt    = (const int*)d_in[2];
    const float* lsc    = (const float*)d_in[3];
    const float* lbi    = (const float*)d_in[4];
    const float* pw     = (const float*)d_in[5];
    const float* alpha  = (const float*)d_in[6];
    float* out = (float*)d_out;

    float* ws   = (float*)d_ws;
    short* wf   = (short*)(ws + WF_OFF);
    float* bias = ws + BIAS_OFF;
    short* yb   = (short*)(ws + Y_OFF);

    prep_wb<<<(NCH * 6 * 64 + 255) / 256, 256, 0, stream>>>(pw, lsc, wf);
    prep_bias<<<COUT, 64, 0, stream>>>(pw, lbi, bias);
    conv_mfma<<<dim3(PIX / 64, B_), 512, 0, stream>>>(x, wf, yb);
    finalize<<<B_ * COUT, 256, 0, stream>>>(x, pad_hv, idt, yb, bias, alpha, out);
}